// Round 1
// baseline (8989.928 us; speedup 1.0000x reference)
//
#include <hip/hip_runtime.h>
#include <hip/hip_bf16.h>

// ---------------------------------------------------------------------------
// GCN: 3x [h = relu( scatter(norm * (hW)[row] -> col) + hW*dinv^2 + b )]
// then out = cat(h1,h2,h3) @ Wlin + blin
// ---------------------------------------------------------------------------

__device__ __forceinline__ void atomicAddF(float* p, float v) {
  unsafeAtomicAdd(p, v);   // native global_atomic_add_f32 on gfx950
}

// ---- degree count: deg[col]++ ---------------------------------------------
__global__ __launch_bounds__(256) void k_deg(const int* __restrict__ col, int E,
                                             int* __restrict__ degi) {
  int e = blockIdx.x * 256 + threadIdx.x;
  if (e < E) atomicAdd(&degi[col[e]], 1);
}

// ---- dinv = rsqrt(1 + deg), in place (int -> float) -----------------------
__global__ __launch_bounds__(256) void k_dinv(void* __restrict__ buf, int N) {
  int n = blockIdx.x * 256 + threadIdx.x;
  if (n < N) {
    int d = ((const int*)buf)[n];
    ((float*)buf)[n] = rsqrtf(1.0f + (float)d);
  }
}

// ---- layer GEMM: hw = A @ W ; hcat_slot = hw*dinv^2 + b -------------------
// A: N x 128 (stride lda), optional relu on load. W: 128x128. 
__global__ __launch_bounds__(256) void k_gemm128(
    const float* __restrict__ A, long long lda, int relu_in,
    const float* __restrict__ W, const float* __restrict__ bias,
    const float* __restrict__ dinv,
    float* __restrict__ hw, float* __restrict__ hcat, int koff, int N) {
  __shared__ __align__(16) float hsT[128][128];  // [k][r ^ (k&28)]
  __shared__ __align__(16) float Ws[128][128];   // [k][c]
  const int tid = threadIdx.x;
  const int n0 = blockIdx.x * 128;
  const int rows = min(128, N - n0);

  // stage W (coalesced, conflict-free)
  #pragma unroll
  for (int i = tid; i < 128 * 32; i += 256) {
    const int k = i >> 5, c = (i & 31) << 2;
    const float4 w = *(const float4*)(W + (size_t)k * 128 + c);
    Ws[k][c] = w.x; Ws[k][c + 1] = w.y; Ws[k][c + 2] = w.z; Ws[k][c + 3] = w.w;
  }
  // stage A transposed with XOR swizzle (write ~4-way, reads conflict-free)
  #pragma unroll
  for (int i = tid; i < 128 * 32; i += 256) {
    const int r = i >> 5, k4 = (i & 31) << 2;
    float4 v = make_float4(0.f, 0.f, 0.f, 0.f);
    if (r < rows) v = *(const float4*)(A + (size_t)(n0 + r) * lda + k4);
    if (relu_in) {
      v.x = fmaxf(v.x, 0.f); v.y = fmaxf(v.y, 0.f);
      v.z = fmaxf(v.z, 0.f); v.w = fmaxf(v.w, 0.f);
    }
    const int s = k4 & 28, c = r ^ s;
    hsT[k4 + 0][c] = v.x; hsT[k4 + 1][c] = v.y;
    hsT[k4 + 2][c] = v.z; hsT[k4 + 3][c] = v.w;
  }
  __syncthreads();

  const int tc = (tid & 15) << 3;   // col base (8 cols)
  const int tr = (tid >> 4) << 3;   // row base (8 rows)
  float acc[8][8] = {};
  #pragma unroll 2
  for (int k = 0; k < 128; ++k) {
    const int s = k & 28;
    const float4 a0 = *(const float4*)&hsT[k][tr ^ s];
    const float4 a1 = *(const float4*)&hsT[k][(tr + 4) ^ s];
    const float4 w0 = *(const float4*)&Ws[k][tc];
    const float4 w1 = *(const float4*)&Ws[k][tc + 4];
    const float a[8] = {a0.x, a0.y, a0.z, a0.w, a1.x, a1.y, a1.z, a1.w};
    const float w[8] = {w0.x, w0.y, w0.z, w0.w, w1.x, w1.y, w1.z, w1.w};
    #pragma unroll
    for (int i = 0; i < 8; ++i)
      #pragma unroll
      for (int j = 0; j < 8; ++j) acc[i][j] = fmaf(a[i], w[j], acc[i][j]);
  }

  #pragma unroll
  for (int i = 0; i < 8; ++i) {
    const int r = tr + i;
    if (r < rows) {
      const int n = n0 + r;
      const float dv = dinv[n];
      const float sn = dv * dv;
      float* hwp = hw + (size_t)n * 128 + tc;
      float* hcp = hcat + (size_t)n * 384 + koff + tc;
      #pragma unroll
      for (int j = 0; j < 8; j += 4) {
        const float4 v = make_float4(acc[i][j], acc[i][j + 1], acc[i][j + 2], acc[i][j + 3]);
        *(float4*)(hwp + j) = v;
        const float4 bb = *(const float4*)(bias + tc + j);
        *(float4*)(hcp + j) = make_float4(v.x * sn + bb.x, v.y * sn + bb.y,
                                          v.z * sn + bb.z, v.w * sn + bb.w);
      }
    }
  }
}

// ---- edge scatter: hcat[col][koff+j] += dinv[row]*dinv[col] * hw[row][j] --
__global__ __launch_bounds__(256) void k_scatter(
    const int* __restrict__ rowi, const int* __restrict__ coli,
    const float* __restrict__ dinv, const float* __restrict__ hw,
    float* __restrict__ hcat, int koff, int E) {
  const int j = (threadIdx.x & 31) << 2;                       // feature offset
  const long long gid = (long long)blockIdx.x * 8 + (threadIdx.x >> 5);
  const long long e0 = gid * 8;
  #pragma unroll
  for (int t = 0; t < 8; ++t) {
    const long long e = e0 + t;
    if (e < E) {
      const int r = rowi[e], c = coli[e];
      const float nrm = dinv[r] * dinv[c];
      const float4 v = *(const float4*)(hw + (size_t)r * 128 + j);
      float* dst = hcat + (size_t)c * 384 + koff + j;
      atomicAddF(dst + 0, nrm * v.x);
      atomicAddF(dst + 1, nrm * v.y);
      atomicAddF(dst + 2, nrm * v.z);
      atomicAddF(dst + 3, nrm * v.w);
    }
  }
}

// ---- final: out = relu(hcat) @ Wlin + blin  (K=384, C=64) -----------------
__global__ __launch_bounds__(256) void k_final(
    const float* __restrict__ hcat, const float* __restrict__ Wlin,
    const float* __restrict__ blin, float* __restrict__ out, int N) {
  __shared__ __align__(16) float hsT[128][128];
  __shared__ __align__(16) float Ws[128][64];
  const int tid = threadIdx.x;
  const int n0 = blockIdx.x * 128;
  const int rows = min(128, N - n0);
  const int tc = (tid & 15) << 2;   // 4 cols
  const int tr = (tid >> 4) << 3;   // 8 rows
  float acc[8][4] = {};

  for (int ck = 0; ck < 3; ++ck) {
    #pragma unroll
    for (int i = tid; i < 128 * 16; i += 256) {
      const int k = i >> 4, c = (i & 15) << 2;
      const float4 w = *(const float4*)(Wlin + (size_t)(ck * 128 + k) * 64 + c);
      Ws[k][c] = w.x; Ws[k][c + 1] = w.y; Ws[k][c + 2] = w.z; Ws[k][c + 3] = w.w;
    }
    #pragma unroll
    for (int i = tid; i < 128 * 32; i += 256) {
      const int r = i >> 5, k4 = (i & 31) << 2;
      float4 v = make_float4(0.f, 0.f, 0.f, 0.f);
      if (r < rows) v = *(const float4*)(hcat + (size_t)(n0 + r) * 384 + ck * 128 + k4);
      v.x = fmaxf(v.x, 0.f); v.y = fmaxf(v.y, 0.f);
      v.z = fmaxf(v.z, 0.f); v.w = fmaxf(v.w, 0.f);
      const int s = k4 & 28, c = r ^ s;
      hsT[k4 + 0][c] = v.x; hsT[k4 + 1][c] = v.y;
      hsT[k4 + 2][c] = v.z; hsT[k4 + 3][c] = v.w;
    }
    __syncthreads();

    #pragma unroll 2
    for (int k = 0; k < 128; ++k) {
      const int s = k & 28;
      const float4 a0 = *(const float4*)&hsT[k][tr ^ s];
      const float4 a1 = *(const float4*)&hsT[k][(tr + 4) ^ s];
      const float4 w0 = *(const float4*)&Ws[k][tc];
      const float a[8] = {a0.x, a0.y, a0.z, a0.w, a1.x, a1.y, a1.z, a1.w};
      const float w[4] = {w0.x, w0.y, w0.z, w0.w};
      #pragma unroll
      for (int i = 0; i < 8; ++i)
        #pragma unroll
        for (int j = 0; j < 4; ++j) acc[i][j] = fmaf(a[i], w[j], acc[i][j]);
    }
    __syncthreads();
  }

  #pragma unroll
  for (int i = 0; i < 8; ++i) {
    const int r = tr + i;
    if (r < rows) {
      const int n = n0 + r;
      const float4 bb = *(const float4*)(blin + tc);
      *(float4*)(out + (size_t)n * 64 + tc) =
          make_float4(acc[i][0] + bb.x, acc[i][1] + bb.y,
                      acc[i][2] + bb.z, acc[i][3] + bb.w);
    }
  }
}

extern "C" void kernel_launch(void* const* d_in, const int* in_sizes, int n_in,
                              void* d_out, int out_size, void* d_ws, size_t ws_size,
                              hipStream_t stream) {
  const float* x    = (const float*)d_in[0];
  const int*   ei   = (const int*)d_in[1];
  const float* W1   = (const float*)d_in[2];
  const float* b1   = (const float*)d_in[3];
  const float* W2   = (const float*)d_in[4];
  const float* b2   = (const float*)d_in[5];
  const float* W3   = (const float*)d_in[6];
  const float* b3   = (const float*)d_in[7];
  const float* Wlin = (const float*)d_in[8];
  const float* blin = (const float*)d_in[9];

  const int N = in_sizes[0] / 128;
  const int E = in_sizes[1] / 2;
  const int* rowi = ei;
  const int* coli = ei + E;

  // workspace layout: dinv | hw (N*128) | hcat (N*384)
  char* ws = (char*)d_ws;
  const size_t dinv_bytes = (((size_t)N * 4) + 255) & ~(size_t)255;
  float* dinv = (float*)ws;
  float* hw   = (float*)(ws + dinv_bytes);
  float* hcat = hw + (size_t)N * 128;

  hipMemsetAsync(dinv, 0, (size_t)N * 4, stream);
  k_deg<<<(E + 255) / 256, 256, 0, stream>>>(coli, E, (int*)dinv);
  k_dinv<<<(N + 255) / 256, 256, 0, stream>>>((void*)dinv, N);

  const float* Wk[3] = {W1, W2, W3};
  const float* bk[3] = {b1, b2, b3};
  const int gemmBlocks = (N + 127) / 128;
  const int scatBlocks = (E + 63) / 64;

  const float* Ain = x;
  long long lda = 128;
  int relu_in = 0;
  for (int k = 0; k < 3; ++k) {
    k_gemm128<<<gemmBlocks, 256, 0, stream>>>(Ain, lda, relu_in, Wk[k], bk[k],
                                              dinv, hw, hcat, k * 128, N);
    k_scatter<<<scatBlocks, 256, 0, stream>>>(rowi, coli, dinv, hw, hcat,
                                              k * 128, E);
    Ain = hcat + k * 128;
    lda = 384;
    relu_in = 1;
  }
  k_final<<<gemmBlocks, 256, 0, stream>>>(hcat, Wlin, blin, (float*)d_out, N);
}

// Round 2
// 1086.520 us; speedup vs baseline: 8.2741x; 8.2741x over previous
//
#include <hip/hip_runtime.h>
#include <hip/hip_bf16.h>

// ---------------------------------------------------------------------------
// GCN via device-built CSR (no f32 atomics):
//   deg -> exclusive scan -> bucket fill sorted_row[]
//   3x [ hw = (relu?)hcat_prev @ W ;  hcat_k[n] = sum_in(norm*hw[r]) + self + b ]
//   out = relu(hcat) @ Wlin + blin
// ---------------------------------------------------------------------------

// ---- degree count: deg[col]++ ---------------------------------------------
__global__ __launch_bounds__(256) void k_deg(const int* __restrict__ col, int E,
                                             int* __restrict__ degi) {
  int e = blockIdx.x * 256 + threadIdx.x;
  if (e < E) atomicAdd(&degi[col[e]], 1);
}

// ---- dinv = rsqrt(1 + deg) ------------------------------------------------
__global__ __launch_bounds__(256) void k_dinv(const int* __restrict__ degi,
                                              float* __restrict__ dinv, int N) {
  int n = blockIdx.x * 256 + threadIdx.x;
  if (n < N) dinv[n] = rsqrtf(1.0f + (float)degi[n]);
}

// ---- scan pass 1: per-1024-chunk exclusive scan + block sums --------------
__global__ __launch_bounds__(256) void k_scan1(const int* __restrict__ degi, int N,
                                               int* __restrict__ offs,
                                               int* __restrict__ bsums) {
  __shared__ int sm[256];
  const int b = blockIdx.x, t = threadIdx.x;
  const int base = b * 1024 + t * 4;
  int v[4];
  #pragma unroll
  for (int i = 0; i < 4; ++i) v[i] = (base + i < N) ? degi[base + i] : 0;
  const int s = v[0] + v[1] + v[2] + v[3];
  sm[t] = s;
  __syncthreads();
  for (int ofs = 1; ofs < 256; ofs <<= 1) {
    const int add = (t >= ofs) ? sm[t - ofs] : 0;
    __syncthreads();
    sm[t] += add;
    __syncthreads();
  }
  if (t == 255) bsums[b] = sm[255];
  int run = sm[t] - s;  // exclusive prefix of this thread's chunk
  #pragma unroll
  for (int i = 0; i < 4; ++i) {
    if (base + i < N) offs[base + i] = run;
    run += v[i];
  }
}

// ---- scan pass 2: exclusive scan of block sums (nb <= 128) ----------------
__global__ __launch_bounds__(128) void k_scan2(int* __restrict__ bsums, int nb) {
  __shared__ int sm[128];
  const int t = threadIdx.x;
  const int v = (t < nb) ? bsums[t] : 0;
  sm[t] = v;
  __syncthreads();
  for (int ofs = 1; ofs < 128; ofs <<= 1) {
    const int add = (t >= ofs) ? sm[t - ofs] : 0;
    __syncthreads();
    sm[t] += add;
    __syncthreads();
  }
  if (t < nb) bsums[t] = sm[t] - v;
}

// ---- scan pass 3: add block offset; copy to cursor ------------------------
__global__ __launch_bounds__(256) void k_scan3(int* __restrict__ offs,
                                               const int* __restrict__ bsums,
                                               int* __restrict__ cursor, int N) {
  const int add = bsums[blockIdx.x];
  const int base = blockIdx.x * 1024 + threadIdx.x * 4;
  #pragma unroll
  for (int i = 0; i < 4; ++i) {
    const int idx = base + i;
    if (idx < N) {
      const int o = offs[idx] + add;
      offs[idx] = o;
      cursor[idx] = o;
    }
  }
}

// ---- bucket fill: sorted_row[pos] = row ------------------------------------
__global__ __launch_bounds__(256) void k_fill(const int* __restrict__ rowi,
                                              const int* __restrict__ coli, int E,
                                              int* __restrict__ cursor,
                                              int* __restrict__ sorted_row) {
  int e = blockIdx.x * 256 + threadIdx.x;
  if (e < E) {
    const int pos = atomicAdd(&cursor[coli[e]], 1);
    sorted_row[pos] = rowi[e];
  }
}

// ---- layer GEMM: hw = (relu?)A @ W ----------------------------------------
__global__ __launch_bounds__(256) void k_gemm128(
    const float* __restrict__ A, long long lda, int relu_in,
    const float* __restrict__ W, float* __restrict__ hw, int N) {
  __shared__ __align__(16) float hsT[128][128];  // [k][r ^ (k&28)]
  __shared__ __align__(16) float Ws[128][128];   // [k][c]
  const int tid = threadIdx.x;
  const int n0 = blockIdx.x * 128;
  const int rows = min(128, N - n0);

  #pragma unroll
  for (int i = tid; i < 128 * 32; i += 256) {
    const int k = i >> 5, c = (i & 31) << 2;
    const float4 w = *(const float4*)(W + (size_t)k * 128 + c);
    Ws[k][c] = w.x; Ws[k][c + 1] = w.y; Ws[k][c + 2] = w.z; Ws[k][c + 3] = w.w;
  }
  #pragma unroll
  for (int i = tid; i < 128 * 32; i += 256) {
    const int r = i >> 5, k4 = (i & 31) << 2;
    float4 v = make_float4(0.f, 0.f, 0.f, 0.f);
    if (r < rows) v = *(const float4*)(A + (size_t)(n0 + r) * lda + k4);
    if (relu_in) {
      v.x = fmaxf(v.x, 0.f); v.y = fmaxf(v.y, 0.f);
      v.z = fmaxf(v.z, 0.f); v.w = fmaxf(v.w, 0.f);
    }
    const int s = k4 & 28, c = r ^ s;
    hsT[k4 + 0][c] = v.x; hsT[k4 + 1][c] = v.y;
    hsT[k4 + 2][c] = v.z; hsT[k4 + 3][c] = v.w;
  }
  __syncthreads();

  const int tc = (tid & 15) << 3;
  const int tr = (tid >> 4) << 3;
  float acc[8][8] = {};
  #pragma unroll 2
  for (int k = 0; k < 128; ++k) {
    const int s = k & 28;
    const float4 a0 = *(const float4*)&hsT[k][tr ^ s];
    const float4 a1 = *(const float4*)&hsT[k][(tr + 4) ^ s];
    const float4 w0 = *(const float4*)&Ws[k][tc];
    const float4 w1 = *(const float4*)&Ws[k][tc + 4];
    const float a[8] = {a0.x, a0.y, a0.z, a0.w, a1.x, a1.y, a1.z, a1.w};
    const float w[8] = {w0.x, w0.y, w0.z, w0.w, w1.x, w1.y, w1.z, w1.w};
    #pragma unroll
    for (int i = 0; i < 8; ++i)
      #pragma unroll
      for (int j = 0; j < 8; ++j) acc[i][j] = fmaf(a[i], w[j], acc[i][j]);
  }

  #pragma unroll
  for (int i = 0; i < 8; ++i) {
    const int r = tr + i;
    if (r < rows) {
      float* hwp = hw + (size_t)(n0 + r) * 128 + tc;
      *(float4*)(hwp + 0) = make_float4(acc[i][0], acc[i][1], acc[i][2], acc[i][3]);
      *(float4*)(hwp + 4) = make_float4(acc[i][4], acc[i][5], acc[i][6], acc[i][7]);
    }
  }
}

// ---- segment aggregate: hcat[n] = sum_in + self + bias (pre-relu) ---------
// one 32-lane group per node, lane owns 4 features
__global__ __launch_bounds__(256) void k_agg(
    const int* __restrict__ offs, const int* __restrict__ degi,
    const int* __restrict__ sorted_row, const float* __restrict__ dinv,
    const float* __restrict__ hw, const float* __restrict__ bias,
    float* __restrict__ hcat, int koff, int N) {
  const int g = (int)((blockIdx.x * 256 + threadIdx.x) >> 5);  // node id
  if (g >= N) return;
  const int j = (threadIdx.x & 31) << 2;
  const float dc = dinv[g];
  const float sn = dc * dc;
  float4 acc = *(const float4*)(hw + (size_t)g * 128 + j);
  acc.x *= sn; acc.y *= sn; acc.z *= sn; acc.w *= sn;

  const int off = offs[g];
  const int end = off + degi[g];
  int e = off;
  for (; e + 1 < end; e += 2) {   // 2-edge unroll: two gathers in flight
    const int r0 = sorted_row[e], r1 = sorted_row[e + 1];
    const float n0 = dinv[r0] * dc, n1 = dinv[r1] * dc;
    const float4 v0 = *(const float4*)(hw + (size_t)r0 * 128 + j);
    const float4 v1 = *(const float4*)(hw + (size_t)r1 * 128 + j);
    acc.x = fmaf(n0, v0.x, acc.x); acc.y = fmaf(n0, v0.y, acc.y);
    acc.z = fmaf(n0, v0.z, acc.z); acc.w = fmaf(n0, v0.w, acc.w);
    acc.x = fmaf(n1, v1.x, acc.x); acc.y = fmaf(n1, v1.y, acc.y);
    acc.z = fmaf(n1, v1.z, acc.z); acc.w = fmaf(n1, v1.w, acc.w);
  }
  if (e < end) {
    const int r0 = sorted_row[e];
    const float n0 = dinv[r0] * dc;
    const float4 v0 = *(const float4*)(hw + (size_t)r0 * 128 + j);
    acc.x = fmaf(n0, v0.x, acc.x); acc.y = fmaf(n0, v0.y, acc.y);
    acc.z = fmaf(n0, v0.z, acc.z); acc.w = fmaf(n0, v0.w, acc.w);
  }
  const float4 bb = *(const float4*)(bias + j);
  *(float4*)(hcat + (size_t)g * 384 + koff + j) =
      make_float4(acc.x + bb.x, acc.y + bb.y, acc.z + bb.z, acc.w + bb.w);
}

// ---- final: out = relu(hcat) @ Wlin + blin  (K=384, C=64) -----------------
__global__ __launch_bounds__(256) void k_final(
    const float* __restrict__ hcat, const float* __restrict__ Wlin,
    const float* __restrict__ blin, float* __restrict__ out, int N) {
  __shared__ __align__(16) float hsT[128][128];
  __shared__ __align__(16) float Ws[128][64];
  const int tid = threadIdx.x;
  const int n0 = blockIdx.x * 128;
  const int rows = min(128, N - n0);
  const int tc = (tid & 15) << 2;
  const int tr = (tid >> 4) << 3;
  float acc[8][4] = {};

  for (int ck = 0; ck < 3; ++ck) {
    #pragma unroll
    for (int i = tid; i < 128 * 16; i += 256) {
      const int k = i >> 4, c = (i & 15) << 2;
      const float4 w = *(const float4*)(Wlin + (size_t)(ck * 128 + k) * 64 + c);
      Ws[k][c] = w.x; Ws[k][c + 1] = w.y; Ws[k][c + 2] = w.z; Ws[k][c + 3] = w.w;
    }
    #pragma unroll
    for (int i = tid; i < 128 * 32; i += 256) {
      const int r = i >> 5, k4 = (i & 31) << 2;
      float4 v = make_float4(0.f, 0.f, 0.f, 0.f);
      if (r < rows) v = *(const float4*)(hcat + (size_t)(n0 + r) * 384 + ck * 128 + k4);
      v.x = fmaxf(v.x, 0.f); v.y = fmaxf(v.y, 0.f);
      v.z = fmaxf(v.z, 0.f); v.w = fmaxf(v.w, 0.f);
      const int s = k4 & 28, c = r ^ s;
      hsT[k4 + 0][c] = v.x; hsT[k4 + 1][c] = v.y;
      hsT[k4 + 2][c] = v.z; hsT[k4 + 3][c] = v.w;
    }
    __syncthreads();

    #pragma unroll 2
    for (int k = 0; k < 128; ++k) {
      const int s = k & 28;
      const float4 a0 = *(const float4*)&hsT[k][tr ^ s];
      const float4 a1 = *(const float4*)&hsT[k][(tr + 4) ^ s];
      const float4 w0 = *(const float4*)&Ws[k][tc];
      const float a[8] = {a0.x, a0.y, a0.z, a0.w, a1.x, a1.y, a1.z, a1.w};
      const float w[4] = {w0.x, w0.y, w0.z, w0.w};
      #pragma unroll
      for (int i = 0; i < 8; ++i)
        #pragma unroll
        for (int j = 0; j < 4; ++j) acc[i][j] = fmaf(a[i], w[j], acc[i][j]);
    }
    __syncthreads();
  }

  #pragma unroll
  for (int i = 0; i < 8; ++i) {
    const int r = tr + i;
    if (r < rows) {
      const float4 bb = *(const float4*)(blin + tc);
      *(float4*)(out + (size_t)(n0 + r) * 64 + tc) =
          make_float4(acc[i][0] + bb.x, acc[i][1] + bb.y,
                      acc[i][2] + bb.z, acc[i][3] + bb.w);
    }
  }
}

extern "C" void kernel_launch(void* const* d_in, const int* in_sizes, int n_in,
                              void* d_out, int out_size, void* d_ws, size_t ws_size,
                              hipStream_t stream) {
  const float* x    = (const float*)d_in[0];
  const int*   ei   = (const int*)d_in[1];
  const float* W1   = (const float*)d_in[2];
  const float* b1   = (const float*)d_in[3];
  const float* W2   = (const float*)d_in[4];
  const float* b2   = (const float*)d_in[5];
  const float* W3   = (const float*)d_in[6];
  const float* b3   = (const float*)d_in[7];
  const float* Wlin = (const float*)d_in[8];
  const float* blin = (const float*)d_in[9];

  const int N = in_sizes[0] / 128;
  const int E = in_sizes[1] / 2;
  const int* rowi = ei;
  const int* coli = ei + E;

  // ws layout: degi | dinv | offs | cursor | bsums | sorted_row | hw | hcat
  char* ws = (char*)d_ws;
  const size_t nb4 = (((size_t)N * 4) + 255) & ~(size_t)255;
  int*   degi       = (int*)ws;                 ws += nb4;
  float* dinv       = (float*)ws;               ws += nb4;
  int*   offs       = (int*)ws;                 ws += nb4;
  int*   cursor     = (int*)ws;                 ws += nb4;
  int*   bsums      = (int*)ws;                 ws += 1024;
  int*   sorted_row = (int*)ws;                 ws += (((size_t)E * 4) + 255) & ~(size_t)255;
  float* hw         = (float*)ws;               ws += (size_t)N * 128 * 4;
  float* hcat       = (float*)ws;

  const int nblk = (N + 1023) / 1024;  // <= 128 for N <= 131072

  hipMemsetAsync(degi, 0, (size_t)N * 4, stream);
  k_deg  <<<(E + 255) / 256, 256, 0, stream>>>(coli, E, degi);
  k_dinv <<<(N + 255) / 256, 256, 0, stream>>>(degi, dinv, N);
  k_scan1<<<nblk, 256, 0, stream>>>(degi, N, offs, bsums);
  k_scan2<<<1, 128, 0, stream>>>(bsums, nblk);
  k_scan3<<<nblk, 256, 0, stream>>>(offs, bsums, cursor, N);
  k_fill <<<(E + 255) / 256, 256, 0, stream>>>(rowi, coli, E, cursor, sorted_row);

  const float* Wk[3] = {W1, W2, W3};
  const float* bk[3] = {b1, b2, b3};
  const int gemmBlocks = (N + 127) / 128;
  const int aggBlocks  = (N + 7) / 8;

  const float* Ain = x;
  long long lda = 128;
  int relu_in = 0;
  for (int k = 0; k < 3; ++k) {
    k_gemm128<<<gemmBlocks, 256, 0, stream>>>(Ain, lda, relu_in, Wk[k], hw, N);
    k_agg<<<aggBlocks, 256, 0, stream>>>(offs, degi, sorted_row, dinv, hw,
                                         bk[k], hcat, k * 128, N);
    Ain = hcat + k * 128;
    lda = 384;
    relu_in = 1;
  }
  k_final<<<gemmBlocks, 256, 0, stream>>>(hcat, Wlin, blin, (float*)d_out, N);
}

// Round 3
// 901.111 us; speedup vs baseline: 9.9765x; 1.2058x over previous
//
#include <hip/hip_runtime.h>
#include <hip/hip_bf16.h>

// ---------------------------------------------------------------------------
// GCN via device-built CSR (no f32 atomics):
//   deg -> exclusive scan -> bucket fill sorted_row[]
//   3x [ hw = dinv * ((relu?)hcat_prev @ W) ;
//        hcat_k[n] = dinv[n]*(hw[n] + sum_in hw[r]) + b ]   (pre-relu stored)
//   out = relu(hcat) @ Wlin + blin
// GEMMs: K-chunked LDS tiles (32KB/48KB) for 3 blocks/CU occupancy.
// ---------------------------------------------------------------------------

// ---- degree count: deg[col]++ ---------------------------------------------
__global__ __launch_bounds__(256) void k_deg(const int* __restrict__ col, int E,
                                             int* __restrict__ degi) {
  int e = blockIdx.x * 256 + threadIdx.x;
  if (e < E) atomicAdd(&degi[col[e]], 1);
}

// ---- dinv = rsqrt(1 + deg) ------------------------------------------------
__global__ __launch_bounds__(256) void k_dinv(const int* __restrict__ degi,
                                              float* __restrict__ dinv, int N) {
  int n = blockIdx.x * 256 + threadIdx.x;
  if (n < N) dinv[n] = rsqrtf(1.0f + (float)degi[n]);
}

// ---- scan pass 1: per-1024-chunk exclusive scan + block sums --------------
__global__ __launch_bounds__(256) void k_scan1(const int* __restrict__ degi, int N,
                                               int* __restrict__ offs,
                                               int* __restrict__ bsums) {
  __shared__ int sm[256];
  const int b = blockIdx.x, t = threadIdx.x;
  const int base = b * 1024 + t * 4;
  int v[4];
  #pragma unroll
  for (int i = 0; i < 4; ++i) v[i] = (base + i < N) ? degi[base + i] : 0;
  const int s = v[0] + v[1] + v[2] + v[3];
  sm[t] = s;
  __syncthreads();
  for (int ofs = 1; ofs < 256; ofs <<= 1) {
    const int add = (t >= ofs) ? sm[t - ofs] : 0;
    __syncthreads();
    sm[t] += add;
    __syncthreads();
  }
  if (t == 255) bsums[b] = sm[255];
  int run = sm[t] - s;
  #pragma unroll
  for (int i = 0; i < 4; ++i) {
    if (base + i < N) offs[base + i] = run;
    run += v[i];
  }
}

// ---- scan pass 2: exclusive scan of block sums (nb <= 128) ----------------
__global__ __launch_bounds__(128) void k_scan2(int* __restrict__ bsums, int nb) {
  __shared__ int sm[128];
  const int t = threadIdx.x;
  const int v = (t < nb) ? bsums[t] : 0;
  sm[t] = v;
  __syncthreads();
  for (int ofs = 1; ofs < 128; ofs <<= 1) {
    const int add = (t >= ofs) ? sm[t - ofs] : 0;
    __syncthreads();
    sm[t] += add;
    __syncthreads();
  }
  if (t < nb) bsums[t] = sm[t] - v;
}

// ---- scan pass 3: add block offset; copy to cursor ------------------------
__global__ __launch_bounds__(256) void k_scan3(int* __restrict__ offs,
                                               const int* __restrict__ bsums,
                                               int* __restrict__ cursor, int N) {
  const int add = bsums[blockIdx.x];
  const int base = blockIdx.x * 1024 + threadIdx.x * 4;
  #pragma unroll
  for (int i = 0; i < 4; ++i) {
    const int idx = base + i;
    if (idx < N) {
      const int o = offs[idx] + add;
      offs[idx] = o;
      cursor[idx] = o;
    }
  }
}

// ---- bucket fill: sorted_row[pos] = row ------------------------------------
__global__ __launch_bounds__(256) void k_fill(const int* __restrict__ rowi,
                                              const int* __restrict__ coli, int E,
                                              int* __restrict__ cursor,
                                              int* __restrict__ sorted_row) {
  int e = blockIdx.x * 256 + threadIdx.x;
  if (e < E) {
    const int pos = atomicAdd(&cursor[coli[e]], 1);
    sorted_row[pos] = rowi[e];
  }
}

// ---- layer GEMM: hw = dinv * ((relu?)A @ W), K=128 chunked by 32 ----------
__global__ __launch_bounds__(256, 3) void k_gemm128(
    const float* __restrict__ A, long long lda, int relu_in,
    const float* __restrict__ W, const float* __restrict__ dinv,
    float* __restrict__ hw, int N) {
  __shared__ __align__(16) float hsT[32][128];  // [k][r ^ (k&28)]
  __shared__ __align__(16) float Ws[32][128];   // [k][c]
  const int tid = threadIdx.x;
  const int n0 = blockIdx.x * 128;
  const int rows = min(128, N - n0);
  const int tc = (tid & 15) << 3;
  const int tr = (tid >> 4) << 3;
  float acc[8][8] = {};

  for (int kc = 0; kc < 128; kc += 32) {
    // stage A chunk transposed + swizzled: 128 rows x 32 k
    #pragma unroll
    for (int i = tid; i < 128 * 8; i += 256) {
      const int r = i >> 3, k4 = (i & 7) << 2;
      float4 v = make_float4(0.f, 0.f, 0.f, 0.f);
      if (r < rows) v = *(const float4*)(A + (size_t)(n0 + r) * lda + kc + k4);
      if (relu_in) {
        v.x = fmaxf(v.x, 0.f); v.y = fmaxf(v.y, 0.f);
        v.z = fmaxf(v.z, 0.f); v.w = fmaxf(v.w, 0.f);
      }
      const int c = r ^ k4;  // k4 in {0,4,...,28} == k4 & 28
      hsT[k4 + 0][c & 127] = v.x; hsT[k4 + 1][c & 127] = v.y;
      hsT[k4 + 2][c & 127] = v.z; hsT[k4 + 3][c & 127] = v.w;
    }
    // stage W chunk: 32 k x 128 c
    #pragma unroll
    for (int i = tid; i < 32 * 32; i += 256) {
      const int k = i >> 5, c = (i & 31) << 2;
      const float4 w = *(const float4*)(W + (size_t)(kc + k) * 128 + c);
      Ws[k][c] = w.x; Ws[k][c + 1] = w.y; Ws[k][c + 2] = w.z; Ws[k][c + 3] = w.w;
    }
    __syncthreads();

    #pragma unroll
    for (int k = 0; k < 32; ++k) {
      const int s = k & 28;
      const float4 a0 = *(const float4*)&hsT[k][tr ^ s];
      const float4 a1 = *(const float4*)&hsT[k][(tr + 4) ^ s];
      const float4 w0 = *(const float4*)&Ws[k][tc];
      const float4 w1 = *(const float4*)&Ws[k][tc + 4];
      const float a[8] = {a0.x, a0.y, a0.z, a0.w, a1.x, a1.y, a1.z, a1.w};
      const float w[8] = {w0.x, w0.y, w0.z, w0.w, w1.x, w1.y, w1.z, w1.w};
      #pragma unroll
      for (int i = 0; i < 8; ++i)
        #pragma unroll
        for (int j = 0; j < 8; ++j) acc[i][j] = fmaf(a[i], w[j], acc[i][j]);
    }
    __syncthreads();
  }

  #pragma unroll
  for (int i = 0; i < 8; ++i) {
    const int r = tr + i;
    if (r < rows) {
      const int n = n0 + r;
      const float dv = dinv[n];
      float* hwp = hw + (size_t)n * 128 + tc;
      *(float4*)(hwp + 0) = make_float4(acc[i][0] * dv, acc[i][1] * dv,
                                        acc[i][2] * dv, acc[i][3] * dv);
      *(float4*)(hwp + 4) = make_float4(acc[i][4] * dv, acc[i][5] * dv,
                                        acc[i][6] * dv, acc[i][7] * dv);
    }
  }
}

// ---- segment aggregate: hcat[n] = dinv[n]*(hw[n] + sum_in hw[r]) + b ------
// one 32-lane group per node, lane owns 4 features; hw is pre-scaled by dinv
__global__ __launch_bounds__(256) void k_agg(
    const int* __restrict__ offs, const int* __restrict__ degi,
    const int* __restrict__ sorted_row, const float* __restrict__ dinv,
    const float* __restrict__ hw, const float* __restrict__ bias,
    float* __restrict__ hcat, int koff, int N) {
  const int g = (int)((blockIdx.x * 256 + threadIdx.x) >> 5);
  if (g >= N) return;
  const int j = (threadIdx.x & 31) << 2;
  float4 acc = *(const float4*)(hw + (size_t)g * 128 + j);  // self term

  const int off = offs[g];
  const int end = off + degi[g];
  int e = off;
  for (; e + 3 < end; e += 4) {  // 4 gathers in flight
    const int r0 = sorted_row[e + 0], r1 = sorted_row[e + 1];
    const int r2 = sorted_row[e + 2], r3 = sorted_row[e + 3];
    const float4 v0 = *(const float4*)(hw + (size_t)r0 * 128 + j);
    const float4 v1 = *(const float4*)(hw + (size_t)r1 * 128 + j);
    const float4 v2 = *(const float4*)(hw + (size_t)r2 * 128 + j);
    const float4 v3 = *(const float4*)(hw + (size_t)r3 * 128 + j);
    acc.x += v0.x + v1.x + v2.x + v3.x;
    acc.y += v0.y + v1.y + v2.y + v3.y;
    acc.z += v0.z + v1.z + v2.z + v3.z;
    acc.w += v0.w + v1.w + v2.w + v3.w;
  }
  for (; e < end; ++e) {
    const int r0 = sorted_row[e];
    const float4 v0 = *(const float4*)(hw + (size_t)r0 * 128 + j);
    acc.x += v0.x; acc.y += v0.y; acc.z += v0.z; acc.w += v0.w;
  }
  const float dc = dinv[g];
  const float4 bb = *(const float4*)(bias + j);
  *(float4*)(hcat + (size_t)g * 384 + koff + j) =
      make_float4(fmaf(dc, acc.x, bb.x), fmaf(dc, acc.y, bb.y),
                  fmaf(dc, acc.z, bb.z), fmaf(dc, acc.w, bb.w));
}

// ---- final: out = relu(hcat) @ Wlin + blin, K=384 chunked by 64 -----------
__global__ __launch_bounds__(256, 3) void k_final(
    const float* __restrict__ hcat, const float* __restrict__ Wlin,
    const float* __restrict__ blin, float* __restrict__ out, int N) {
  __shared__ __align__(16) float hsT[64][128];  // [k][r ^ (k&28)]
  __shared__ __align__(16) float Ws[64][64];    // [k][c]
  const int tid = threadIdx.x;
  const int n0 = blockIdx.x * 128;
  const int rows = min(128, N - n0);
  const int tc = (tid & 15) << 2;
  const int tr = (tid >> 4) << 3;
  float acc[8][4] = {};

  for (int kc = 0; kc < 384; kc += 64) {
    // stage A chunk: 128 rows x 64 k
    #pragma unroll
    for (int i = tid; i < 128 * 16; i += 256) {
      const int r = i >> 4, k4 = (i & 15) << 2;
      float4 v = make_float4(0.f, 0.f, 0.f, 0.f);
      if (r < rows) v = *(const float4*)(hcat + (size_t)(n0 + r) * 384 + kc + k4);
      v.x = fmaxf(v.x, 0.f); v.y = fmaxf(v.y, 0.f);
      v.z = fmaxf(v.z, 0.f); v.w = fmaxf(v.w, 0.f);
      const int s = k4 & 28, c = r ^ s;
      hsT[k4 + 0][c] = v.x; hsT[k4 + 1][c] = v.y;
      hsT[k4 + 2][c] = v.z; hsT[k4 + 3][c] = v.w;
    }
    // stage W chunk: 64 k x 64 c
    #pragma unroll
    for (int i = tid; i < 64 * 16; i += 256) {
      const int k = i >> 4, c = (i & 15) << 2;
      const float4 w = *(const float4*)(Wlin + (size_t)(kc + k) * 64 + c);
      Ws[k][c] = w.x; Ws[k][c + 1] = w.y; Ws[k][c + 2] = w.z; Ws[k][c + 3] = w.w;
    }
    __syncthreads();

    #pragma unroll
    for (int k = 0; k < 64; ++k) {
      const int s = k & 28;
      const float4 a0 = *(const float4*)&hsT[k][tr ^ s];
      const float4 a1 = *(const float4*)&hsT[k][(tr + 4) ^ s];
      const float4 w0 = *(const float4*)&Ws[k][tc];
      const float a[8] = {a0.x, a0.y, a0.z, a0.w, a1.x, a1.y, a1.z, a1.w};
      const float w[4] = {w0.x, w0.y, w0.z, w0.w};
      #pragma unroll
      for (int i = 0; i < 8; ++i)
        #pragma unroll
        for (int j = 0; j < 4; ++j) acc[i][j] = fmaf(a[i], w[j], acc[i][j]);
    }
    __syncthreads();
  }

  #pragma unroll
  for (int i = 0; i < 8; ++i) {
    const int r = tr + i;
    if (r < rows) {
      const float4 bb = *(const float4*)(blin + tc);
      *(float4*)(out + (size_t)(n0 + r) * 64 + tc) =
          make_float4(acc[i][0] + bb.x, acc[i][1] + bb.y,
                      acc[i][2] + bb.z, acc[i][3] + bb.w);
    }
  }
}

extern "C" void kernel_launch(void* const* d_in, const int* in_sizes, int n_in,
                              void* d_out, int out_size, void* d_ws, size_t ws_size,
                              hipStream_t stream) {
  const float* x    = (const float*)d_in[0];
  const int*   ei   = (const int*)d_in[1];
  const float* W1   = (const float*)d_in[2];
  const float* b1   = (const float*)d_in[3];
  const float* W2   = (const float*)d_in[4];
  const float* b2   = (const float*)d_in[5];
  const float* W3   = (const float*)d_in[6];
  const float* b3   = (const float*)d_in[7];
  const float* Wlin = (const float*)d_in[8];
  const float* blin = (const float*)d_in[9];

  const int N = in_sizes[0] / 128;
  const int E = in_sizes[1] / 2;
  const int* rowi = ei;
  const int* coli = ei + E;

  // ws layout: degi | dinv | offs | cursor | bsums | sorted_row | hw | hcat
  char* ws = (char*)d_ws;
  const size_t nb4 = (((size_t)N * 4) + 255) & ~(size_t)255;
  int*   degi       = (int*)ws;                 ws += nb4;
  float* dinv       = (float*)ws;               ws += nb4;
  int*   offs       = (int*)ws;                 ws += nb4;
  int*   cursor     = (int*)ws;                 ws += nb4;
  int*   bsums      = (int*)ws;                 ws += 1024;
  int*   sorted_row = (int*)ws;                 ws += (((size_t)E * 4) + 255) & ~(size_t)255;
  float* hw         = (float*)ws;               ws += (size_t)N * 128 * 4;
  float* hcat       = (float*)ws;

  const int nblk = (N + 1023) / 1024;  // <= 128 for N <= 131072

  hipMemsetAsync(degi, 0, (size_t)N * 4, stream);
  k_deg  <<<(E + 255) / 256, 256, 0, stream>>>(coli, E, degi);
  k_dinv <<<(N + 255) / 256, 256, 0, stream>>>(degi, dinv, N);
  k_scan1<<<nblk, 256, 0, stream>>>(degi, N, offs, bsums);
  k_scan2<<<1, 128, 0, stream>>>(bsums, nblk);
  k_scan3<<<nblk, 256, 0, stream>>>(offs, bsums, cursor, N);
  k_fill <<<(E + 255) / 256, 256, 0, stream>>>(rowi, coli, E, cursor, sorted_row);

  const float* Wk[3] = {W1, W2, W3};
  const float* bk[3] = {b1, b2, b3};
  const int gemmBlocks = (N + 127) / 128;
  const int aggBlocks  = (N + 7) / 8;

  const float* Ain = x;
  long long lda = 128;
  int relu_in = 0;
  for (int k = 0; k < 3; ++k) {
    k_gemm128<<<gemmBlocks, 256, 0, stream>>>(Ain, lda, relu_in, Wk[k], dinv, hw, N);
    k_agg<<<aggBlocks, 256, 0, stream>>>(offs, degi, sorted_row, dinv, hw,
                                         bk[k], hcat, k * 128, N);
    Ain = hcat + k * 128;
    lda = 384;
    relu_in = 1;
  }
  k_final<<<gemmBlocks, 256, 0, stream>>>(hcat, Wlin, blin, (float*)d_out, N);
}